// Round 9
// baseline (676.854 us; speedup 1.0000x reference)
//
#include <hip/hip_runtime.h>
#include <math.h>

#define T_TOK 4096
#define DM 1024
#define HID 4096
#define NEXP 8
#define MAXT 39   // max total 128-row tiles: 4096/128 + 7

typedef unsigned short u16;
typedef __attribute__((ext_vector_type(8))) short short8;
typedef __attribute__((ext_vector_type(4))) float f32x4;

__device__ __forceinline__ u16 f2bf(float f){
  unsigned u = __float_as_uint(f);
  u += 0x7FFF + ((u >> 16) & 1);
  return (u16)(u >> 16);
}

// ---- workspace layout (byte offsets) ----
#define GATE_OFF   0u          // float[4096]
#define CNT_OFF    16384u      // int[8]
#define LIST_OFF   16512u      // int[8][4096]
#define PROBS_OFF  147584u     // float[4096][8]
#define XB_OFF     278656u     // bf16[4096][1024]
#define H_OFF      8667264u    // bf16[4096][4096]
#define W1B_OFF    42221696u   // bf16[8][4096][1024] (dead after GEMM1 -> PART)
#define PART_OFF   W1B_OFF     // float[4][4096][1024] = 64MB, exact overlay
#define W2B_OFF    109330560u  // bf16[8][1024][4096]

__device__ __forceinline__ void glds16(const void* g, void* l){
  __builtin_amdgcn_global_load_lds((const __attribute__((address_space(1))) void*)g,
                                   (__attribute__((address_space(3))) void*)l, 16, 0, 0);
}

__global__ void zero_cnt_kernel(int* cnt){
  if (threadIdx.x < NEXP) cnt[threadIdx.x] = 0;
}

// fp32 -> bf16 streaming convert for BOTH weight tensors in one launch.
// blocks [0,16384): w1 (32M elems); [16384,32768): w2 (32M elems)
__global__ __launch_bounds__(256) void cvt2_kernel(const float* __restrict__ w1,
                                                   const float* __restrict__ w2,
                                                   u16* __restrict__ w1b,
                                                   u16* __restrict__ w2b){
  int b = blockIdx.x;
  const float* src; u16* dst; size_t i;
  if (b < 16384){ src = w1; dst = w1b; i = (size_t)b * 256 + threadIdx.x; }
  else          { src = w2; dst = w2b; i = (size_t)(b - 16384) * 256 + threadIdx.x; }
  const float4* s = (const float4*)src + i * 2;
  float4 a = s[0], c = s[1];
  uint4 p;
  p.x = (unsigned)f2bf(a.x) | ((unsigned)f2bf(a.y) << 16);
  p.y = (unsigned)f2bf(a.z) | ((unsigned)f2bf(a.w) << 16);
  p.z = (unsigned)f2bf(c.x) | ((unsigned)f2bf(c.y) << 16);
  p.w = (unsigned)f2bf(c.z) | ((unsigned)f2bf(c.w) << 16);
  ((uint4*)dst)[i] = p;
}

// one wave per token: gating + routing + x->bf16 conversion
__global__ __launch_bounds__(256) void gate_kernel(
    const float* __restrict__ x, const float* __restrict__ gw,
    float* __restrict__ gateo, int* __restrict__ cnt, int* __restrict__ list,
    float* __restrict__ probs, u16* __restrict__ xb)
{
  int tid = threadIdx.x;
  int lane = tid & 63;
  int w = tid >> 6;
  int t = blockIdx.x * 4 + w;

  const float4* x4 = (const float4*)(x + (size_t)t * DM);
  const float4* g4 = (const float4*)gw;

  float acc[8] = {0,0,0,0,0,0,0,0};
  #pragma unroll
  for (int i = 0; i < 4; i++){
    int p = i * 64 + lane;
    float4 xv = x4[p];
    ushort4 pk;
    pk.x = f2bf(xv.x); pk.y = f2bf(xv.y); pk.z = f2bf(xv.z); pk.w = f2bf(xv.w);
    *(ushort4*)&xb[(size_t)t * DM + (size_t)p * 4] = pk;
    #pragma unroll
    for (int e = 0; e < NEXP; e++){
      float4 gv = g4[e * 256 + p];
      acc[e] += xv.x * gv.x + xv.y * gv.y + xv.z * gv.z + xv.w * gv.w;
    }
  }
  #pragma unroll
  for (int e = 0; e < NEXP; e++){
    #pragma unroll
    for (int off = 32; off; off >>= 1)
      acc[e] += __shfl_xor(acc[e], off);
  }
  if (lane == 0){
    float mx = acc[0];
    #pragma unroll
    for (int e = 1; e < NEXP; e++) mx = fmaxf(mx, acc[e]);
    float p[8]; float s = 0.f;
    #pragma unroll
    for (int e = 0; e < NEXP; e++){ p[e] = expf(acc[e] - mx); s += p[e]; }
    float inv = 1.f / s;
    int be = 0; float bp = p[0];
    #pragma unroll
    for (int e = 1; e < NEXP; e++){ if (p[e] > bp){ bp = p[e]; be = e; } }
    #pragma unroll
    for (int e = 0; e < NEXP; e++) probs[(size_t)t * 8 + e] = p[e] * inv;
    gateo[t] = bp * inv;
    int pos = atomicAdd(&cnt[be], 1);
    list[be * T_TOK + pos] = t;
  }
}

// deterministic aux-loss reduction, one block
__global__ __launch_bounds__(256) void aux_kernel(
    const float* __restrict__ probs, const int* __restrict__ cnt,
    float* __restrict__ aux_out)
{
  __shared__ float sm[256 * 8];
  int tid = threadIdx.x;
  float s[8] = {0,0,0,0,0,0,0,0};
  for (int i = 0; i < 16; i++){
    int t = i * 256 + tid;
    #pragma unroll
    for (int e = 0; e < 8; e++) s[e] += probs[(size_t)t * 8 + e];
  }
  #pragma unroll
  for (int e = 0; e < 8; e++) sm[tid * 8 + e] = s[e];
  __syncthreads();
  for (int st = 128; st; st >>= 1){
    if (tid < st){
      #pragma unroll
      for (int e = 0; e < 8; e++) sm[tid * 8 + e] += sm[(tid + st) * 8 + e];
    }
    __syncthreads();
  }
  if (tid == 0){
    float a = 0.f;
    #pragma unroll
    for (int e = 0; e < 8; e++){
      float f = (float)cnt[e] / (float)T_TOK;
      float P = sm[e] / (float)T_TOK;
      a += f * P;
    }
    aux_out[0] = 0.01f * (float)NEXP * a;
  }
}

// Grouped GEMM, m97 structure: 128x128 tile, BK=64, 4 waves (2x2), single 32KB
// LDS buffer, glds-direct staging, 2 barriers per K-step.
// OCCUPANCY IS THE LEVER: launch_bounds(256,5) -> 5 blocks/CU (LDS 5x32=160KB,
// VGPR<=102), 20 waves/CU; grid 1248 <= 1280 slots -> single dispatch round.
// bid = (sk*MAXT + t)*NT + nt; block scans cnt[] to decode t -> (e, mt).
// PHASE2=false: A=xb, B=w1b -> h = gelu(acc+b1) bf16
// PHASE2=true : A=h,  B=w2b -> PART[sk][tok][col] = acc (+b2 if sk==0) fp32
template<int ASTR, int BSTR, int NTOT, int NT, int KS, bool PHASE2>
__global__ __launch_bounds__(256, 5) void ffn_gemm(
    const u16*  __restrict__ Aall,
    const u16*  __restrict__ Bb,
    const float* __restrict__ bias,
    const int*  __restrict__ cnt,
    const int*  __restrict__ list,
    u16*  __restrict__ hOut,
    float* __restrict__ pOut)
{
  int bid = blockIdx.x;
  int nt = bid % NT;
  int r1 = bid / NT;
  int t  = r1 % MAXT;
  int sk = r1 / MAXT;

  // decode compacted tile index -> (e, mt)   (128-row tiles)
  int e = -1, mt = 0, accT = 0;
  #pragma unroll
  for (int i = 0; i < NEXP; i++){
    int nti = (cnt[i] + 127) >> 7;
    if (e < 0 && t < accT + nti){ e = i; mt = t - accT; }
    accT += nti;
  }
  if (e < 0) return;
  int ne = cnt[e];
  int m0 = mt * 128;
  const int* lst = list + e * T_TOK;
  int n0 = nt * 128;
  int koff = sk * (KS * 64);

  __shared__ u16 As[8192];           // [128][64] swizzled, 16KB
  __shared__ u16 Bs[8192];

  int tid  = threadIdx.x;
  int lane = tid & 63;
  int w    = tid >> 6;               // 4 waves
  int wm = w >> 1, wn = w & 1;       // 2M x 2N; wave out 64x64
  int fr = lane & 15, fq = lane >> 4;

  // staging: 16 segs of 1KB (8 rows x 64 cols) per matrix; wave owns 4 of each.
  // lane l -> row seg*8+(l>>3); fetches global chunk g=(l&7)^(row&7) so
  // LDS[row][slot] holds global chunk slot^(row&7) (both-sides swizzle).
  const u16* aS[4]; const u16* bS[4]; int dst[4];
  #pragma unroll
  for (int i = 0; i < 4; i++){
    int seg = w * 4 + i;
    int r   = seg * 8 + (lane >> 3);
    int g   = (lane & 7) ^ (r & 7);
    int mrow = m0 + r; if (mrow > ne - 1) mrow = ne - 1;
    aS[i] = Aall + (size_t)lst[mrow] * ASTR + koff + g * 8;
    bS[i] = Bb + (size_t)e * NTOT * BSTR + (size_t)(n0 + r) * BSTR + koff + g * 8;
    dst[i] = seg * 512;
  }

  f32x4 acc[4][4];
  #pragma unroll
  for (int m = 0; m < 4; m++)
    #pragma unroll
    for (int n = 0; n < 4; n++)
      acc[m][n] = (f32x4){0.f, 0.f, 0.f, 0.f};

  for (int ks = 0; ks < KS; ++ks){
    if (ks) __syncthreads();         // all waves done reading LDS (lgkm drained)
    size_t ko = (size_t)ks * 64;
    #pragma unroll
    for (int i = 0; i < 4; i++) glds16(aS[i] + ko, &As[dst[i]]);
    #pragma unroll
    for (int i = 0; i < 4; i++) glds16(bS[i] + ko, &Bs[dst[i]]);
    __syncthreads();                 // vmcnt(0) drain: tile resident
    #pragma unroll
    for (int kc = 0; kc < 2; kc++){
      short8 afr[4], bfr[4];
      #pragma unroll
      for (int m = 0; m < 4; m++){
        int row  = wm * 64 + m * 16 + fr;
        int slot = (kc * 4 + fq) ^ (row & 7);
        afr[m] = *(const short8*)&As[row * 64 + slot * 8];
      }
      #pragma unroll
      for (int n = 0; n < 4; n++){
        int row  = wn * 64 + n * 16 + fr;
        int slot = (kc * 4 + fq) ^ (row & 7);
        bfr[n] = *(const short8*)&Bs[row * 64 + slot * 8];
      }
      #pragma unroll
      for (int m = 0; m < 4; m++)
        #pragma unroll
        for (int n = 0; n < 4; n++)
          acc[m][n] = __builtin_amdgcn_mfma_f32_16x16x32_bf16(afr[m], bfr[n], acc[m][n], 0, 0, 0);
    }
  }

  // epilogue: C frag layout col = lane&15, row = (lane>>4)*4 + i
  #pragma unroll
  for (int n = 0; n < 4; n++){
    int col = n0 + wn * 64 + n * 16 + fr;
    float bv = bias[(size_t)e * NTOT + col];
    if (PHASE2 && sk != 0) bv = 0.f;
    #pragma unroll
    for (int m = 0; m < 4; m++){
      int rbase = m0 + wm * 64 + m * 16 + fq * 4;
      f32x4 v = acc[m][n];
      #pragma unroll
      for (int i = 0; i < 4; i++){
        int mrow = rbase + i;
        if (mrow < ne){
          int tok = lst[mrow];
          float val = v[i] + bv;
          if (PHASE2){
            pOut[((size_t)sk * T_TOK + tok) * DM + col] = val;
          } else {
            float gl = 0.5f * val * (1.0f + erff(val * 0.70710678118654752f));
            hOut[(size_t)tok * HID + col] = f2bf(gl);
          }
        }
      }
    }
  }
}

// out = gate * (part0+part1+part2+part3)   (b2 already in part0)
__global__ __launch_bounds__(256) void reduce_kernel(
    const float* __restrict__ part, const float* __restrict__ gate,
    float* __restrict__ out)
{
  size_t i = (size_t)blockIdx.x * 256 + threadIdx.x;     // float4 index
  constexpr size_t S = (size_t)T_TOK * DM / 4;
  const float4* p = (const float4*)part;
  float4 a = p[i], b = p[i + S], c = p[i + 2 * S], d = p[i + 3 * S];
  float g = gate[i >> 8];                                // 256 float4 per row
  float4 o;
  o.x = (a.x + b.x + c.x + d.x) * g;
  o.y = (a.y + b.y + c.y + d.y) * g;
  o.z = (a.z + b.z + c.z + d.z) * g;
  o.w = (a.w + b.w + c.w + d.w) * g;
  ((float4*)out)[i] = o;
}

extern "C" void kernel_launch(void* const* d_in, const int* in_sizes, int n_in,
                              void* d_out, int out_size, void* d_ws, size_t ws_size,
                              hipStream_t stream) {
  const float* x   = (const float*)d_in[0];
  const float* gw  = (const float*)d_in[1];
  const float* w1  = (const float*)d_in[2];
  const float* b1  = (const float*)d_in[3];
  const float* w2  = (const float*)d_in[4];
  const float* b2  = (const float*)d_in[5];

  char* ws = (char*)d_ws;
  float* gateo = (float*)(ws + GATE_OFF);
  int*   cnt   = (int*)  (ws + CNT_OFF);
  int*   list  = (int*)  (ws + LIST_OFF);
  float* probs = (float*)(ws + PROBS_OFF);
  u16*   xb    = (u16*)  (ws + XB_OFF);
  u16*   h     = (u16*)  (ws + H_OFF);
  u16*   w1b   = (u16*)  (ws + W1B_OFF);
  float* part  = (float*)(ws + PART_OFF);   // overlays w1b (dead after GEMM1)
  u16*   w2b   = (u16*)  (ws + W2B_OFF);

  float* out = (float*)d_out;
  float* aux = out + (size_t)T_TOK * DM;

  hipLaunchKernelGGL(zero_cnt_kernel, dim3(1), dim3(64), 0, stream, cnt);
  hipLaunchKernelGGL(gate_kernel, dim3(T_TOK / 4), dim3(256), 0, stream,
                     x, gw, gateo, cnt, list, probs, xb);
  hipLaunchKernelGGL(aux_kernel, dim3(1), dim3(256), 0, stream, probs, cnt, aux);
  hipLaunchKernelGGL(cvt2_kernel, dim3(32768), dim3(256), 0, stream, w1, w2, w1b, w2b);

  // GEMM1: xb[tok,1024] x w1b[e][4096][1024] -> h[tok][4096]
  //   ASTR=1024, BSTR=1024, NTOT=4096, NT=32, KS=16, grid = 39*32 = 1248
  hipLaunchKernelGGL((ffn_gemm<DM, DM, HID, 32, 16, false>),
                     dim3(MAXT * 32), dim3(256), 0, stream,
                     xb, w1b, b1, cnt, list, h, (float*)nullptr);
  // GEMM2: h[tok,4096] x w2b[e][1024][4096] -> PART[sk][tok][1024], split-K=4
  //   ASTR=4096, BSTR=4096, NTOT=1024, NT=8, KS=16, grid = 4*39*8 = 1248
  hipLaunchKernelGGL((ffn_gemm<HID, HID, DM, 8, 16, true>),
                     dim3(4 * MAXT * 8), dim3(256), 0, stream,
                     h, w2b, b2, cnt, list, (u16*)nullptr, part);
  hipLaunchKernelGGL(reduce_kernel, dim3(T_TOK * DM / 4 / 256), dim3(256), 0, stream,
                     part, gateo, out);
}

// Round 10
// 329.488 us; speedup vs baseline: 2.0543x; 2.0543x over previous
//
#include <hip/hip_runtime.h>
#include <math.h>

#define T_TOK 4096
#define DM 1024
#define HID 4096
#define NEXP 8
#define MAXT 39   // max total 128-row tiles: 4096/128 + 7

typedef unsigned short u16;
typedef __attribute__((ext_vector_type(8))) short short8;
typedef __attribute__((ext_vector_type(4))) float f32x4;

__device__ __forceinline__ u16 f2bf(float f){
  unsigned u = __float_as_uint(f);
  u += 0x7FFF + ((u >> 16) & 1);
  return (u16)(u >> 16);
}

// ---- workspace layout (byte offsets) ----
#define GATE_OFF   0u          // float[4096]
#define CNT_OFF    16384u      // int[8]
#define LIST_OFF   16512u      // int[8][4096]
#define PROBS_OFF  147584u     // float[4096][8]
#define XB_OFF     278656u     // bf16[4096][1024]
#define H_OFF      8667264u    // bf16[4096][4096]
#define W1B_OFF    42221696u   // bf16[8][4096][1024] (dead after GEMM1 -> PART)
#define PART_OFF   W1B_OFF     // float[4][4096][1024] = 64MB, exact overlay
#define W2B_OFF    109330560u  // bf16[8][1024][4096]

__device__ __forceinline__ void glds16(const void* g, void* l){
  __builtin_amdgcn_global_load_lds((const __attribute__((address_space(1))) void*)g,
                                   (__attribute__((address_space(3))) void*)l, 16, 0, 0);
}

__global__ void zero_cnt_kernel(int* cnt){
  if (threadIdx.x < NEXP) cnt[threadIdx.x] = 0;
}

// fp32 -> bf16 streaming convert for BOTH weight tensors in one launch.
// blocks [0,16384): w1 (32M elems); [16384,32768): w2 (32M elems)
__global__ __launch_bounds__(256) void cvt2_kernel(const float* __restrict__ w1,
                                                   const float* __restrict__ w2,
                                                   u16* __restrict__ w1b,
                                                   u16* __restrict__ w2b){
  int b = blockIdx.x;
  const float* src; u16* dst; size_t i;
  if (b < 16384){ src = w1; dst = w1b; i = (size_t)b * 256 + threadIdx.x; }
  else          { src = w2; dst = w2b; i = (size_t)(b - 16384) * 256 + threadIdx.x; }
  const float4* s = (const float4*)src + i * 2;
  float4 a = s[0], c = s[1];
  uint4 p;
  p.x = (unsigned)f2bf(a.x) | ((unsigned)f2bf(a.y) << 16);
  p.y = (unsigned)f2bf(a.z) | ((unsigned)f2bf(a.w) << 16);
  p.z = (unsigned)f2bf(c.x) | ((unsigned)f2bf(c.y) << 16);
  p.w = (unsigned)f2bf(c.z) | ((unsigned)f2bf(c.w) << 16);
  ((uint4*)dst)[i] = p;
}

// one wave per token: gating + routing + x->bf16 conversion
__global__ __launch_bounds__(256) void gate_kernel(
    const float* __restrict__ x, const float* __restrict__ gw,
    float* __restrict__ gateo, int* __restrict__ cnt, int* __restrict__ list,
    float* __restrict__ probs, u16* __restrict__ xb)
{
  int tid = threadIdx.x;
  int lane = tid & 63;
  int w = tid >> 6;
  int t = blockIdx.x * 4 + w;

  const float4* x4 = (const float4*)(x + (size_t)t * DM);
  const float4* g4 = (const float4*)gw;

  float acc[8] = {0,0,0,0,0,0,0,0};
  #pragma unroll
  for (int i = 0; i < 4; i++){
    int p = i * 64 + lane;
    float4 xv = x4[p];
    ushort4 pk;
    pk.x = f2bf(xv.x); pk.y = f2bf(xv.y); pk.z = f2bf(xv.z); pk.w = f2bf(xv.w);
    *(ushort4*)&xb[(size_t)t * DM + (size_t)p * 4] = pk;
    #pragma unroll
    for (int e = 0; e < NEXP; e++){
      float4 gv = g4[e * 256 + p];
      acc[e] += xv.x * gv.x + xv.y * gv.y + xv.z * gv.z + xv.w * gv.w;
    }
  }
  #pragma unroll
  for (int e = 0; e < NEXP; e++){
    #pragma unroll
    for (int off = 32; off; off >>= 1)
      acc[e] += __shfl_xor(acc[e], off);
  }
  if (lane == 0){
    float mx = acc[0];
    #pragma unroll
    for (int e = 1; e < NEXP; e++) mx = fmaxf(mx, acc[e]);
    float p[8]; float s = 0.f;
    #pragma unroll
    for (int e = 0; e < NEXP; e++){ p[e] = expf(acc[e] - mx); s += p[e]; }
    float inv = 1.f / s;
    int be = 0; float bp = p[0];
    #pragma unroll
    for (int e = 1; e < NEXP; e++){ if (p[e] > bp){ bp = p[e]; be = e; } }
    #pragma unroll
    for (int e = 0; e < NEXP; e++) probs[(size_t)t * 8 + e] = p[e] * inv;
    gateo[t] = bp * inv;
    int pos = atomicAdd(&cnt[be], 1);
    list[be * T_TOK + pos] = t;
  }
}

// deterministic aux-loss reduction, one block
__global__ __launch_bounds__(256) void aux_kernel(
    const float* __restrict__ probs, const int* __restrict__ cnt,
    float* __restrict__ aux_out)
{
  __shared__ float sm[256 * 8];
  int tid = threadIdx.x;
  float s[8] = {0,0,0,0,0,0,0,0};
  for (int i = 0; i < 16; i++){
    int t = i * 256 + tid;
    #pragma unroll
    for (int e = 0; e < 8; e++) s[e] += probs[(size_t)t * 8 + e];
  }
  #pragma unroll
  for (int e = 0; e < 8; e++) sm[tid * 8 + e] = s[e];
  __syncthreads();
  for (int st = 128; st; st >>= 1){
    if (tid < st){
      #pragma unroll
      for (int e = 0; e < 8; e++) sm[tid * 8 + e] += sm[(tid + st) * 8 + e];
    }
    __syncthreads();
  }
  if (tid == 0){
    float a = 0.f;
    #pragma unroll
    for (int e = 0; e < 8; e++){
      float f = (float)cnt[e] / (float)T_TOK;
      float P = sm[e] / (float)T_TOK;
      a += f * P;
    }
    aux_out[0] = 0.01f * (float)NEXP * a;
  }
}

// Grouped GEMM, m97 structure: 128x128 tile, BK=64, 4 waves (2x2), single 32KB
// LDS buffer, glds-direct staging, 2 barriers per K-step.
// OCCUPANCY: launch_bounds(256,4) -> 4 blocks/CU (VGPR cap 128 >= 76 used: NO
// spill; 5 waves/EU spilled acc -> 3x regression, R9), LDS 4x32=128KB, 1024
// slots -> ~1 dispatch round for ~1024 live blocks.
// bid = (sk*MAXT + t)*NT + nt; block scans cnt[] to decode t -> (e, mt).
// PHASE2=false: A=xb, B=w1b -> h = gelu(acc+b1) bf16
// PHASE2=true : A=h,  B=w2b -> PART[sk][tok][col] = acc (+b2 if sk==0) fp32
template<int ASTR, int BSTR, int NTOT, int NT, int KS, bool PHASE2>
__global__ __launch_bounds__(256, 4) void ffn_gemm(
    const u16*  __restrict__ Aall,
    const u16*  __restrict__ Bb,
    const float* __restrict__ bias,
    const int*  __restrict__ cnt,
    const int*  __restrict__ list,
    u16*  __restrict__ hOut,
    float* __restrict__ pOut)
{
  int bid = blockIdx.x;
  int nt = bid % NT;
  int r1 = bid / NT;
  int t  = r1 % MAXT;
  int sk = r1 / MAXT;

  // decode compacted tile index -> (e, mt)   (128-row tiles)
  int e = -1, mt = 0, accT = 0;
  #pragma unroll
  for (int i = 0; i < NEXP; i++){
    int nti = (cnt[i] + 127) >> 7;
    if (e < 0 && t < accT + nti){ e = i; mt = t - accT; }
    accT += nti;
  }
  if (e < 0) return;
  int ne = cnt[e];
  int m0 = mt * 128;
  const int* lst = list + e * T_TOK;
  int n0 = nt * 128;
  int koff = sk * (KS * 64);

  __shared__ u16 As[8192];           // [128][64] swizzled, 16KB
  __shared__ u16 Bs[8192];

  int tid  = threadIdx.x;
  int lane = tid & 63;
  int w    = tid >> 6;               // 4 waves
  int wm = w >> 1, wn = w & 1;       // 2M x 2N; wave out 64x64
  int fr = lane & 15, fq = lane >> 4;

  // staging: 16 segs of 1KB (8 rows x 64 cols) per matrix; wave owns 4 of each.
  // lane l -> row seg*8+(l>>3); fetches global chunk g=(l&7)^(row&7) so
  // LDS[row][slot] holds global chunk slot^(row&7) (both-sides swizzle).
  const u16* aS[4]; const u16* bS[4]; int dst[4];
  #pragma unroll
  for (int i = 0; i < 4; i++){
    int seg = w * 4 + i;
    int r   = seg * 8 + (lane >> 3);
    int g   = (lane & 7) ^ (r & 7);
    int mrow = m0 + r; if (mrow > ne - 1) mrow = ne - 1;
    aS[i] = Aall + (size_t)lst[mrow] * ASTR + koff + g * 8;
    bS[i] = Bb + (size_t)e * NTOT * BSTR + (size_t)(n0 + r) * BSTR + koff + g * 8;
    dst[i] = seg * 512;
  }

  f32x4 acc[4][4];
  #pragma unroll
  for (int m = 0; m < 4; m++)
    #pragma unroll
    for (int n = 0; n < 4; n++)
      acc[m][n] = (f32x4){0.f, 0.f, 0.f, 0.f};

  for (int ks = 0; ks < KS; ++ks){
    if (ks) __syncthreads();         // all waves done reading LDS (lgkm drained)
    size_t ko = (size_t)ks * 64;
    #pragma unroll
    for (int i = 0; i < 4; i++) glds16(aS[i] + ko, &As[dst[i]]);
    #pragma unroll
    for (int i = 0; i < 4; i++) glds16(bS[i] + ko, &Bs[dst[i]]);
    __syncthreads();                 // vmcnt(0) drain: tile resident
    #pragma unroll
    for (int kc = 0; kc < 2; kc++){
      short8 afr[4], bfr[4];
      #pragma unroll
      for (int m = 0; m < 4; m++){
        int row  = wm * 64 + m * 16 + fr;
        int slot = (kc * 4 + fq) ^ (row & 7);
        afr[m] = *(const short8*)&As[row * 64 + slot * 8];
      }
      #pragma unroll
      for (int n = 0; n < 4; n++){
        int row  = wn * 64 + n * 16 + fr;
        int slot = (kc * 4 + fq) ^ (row & 7);
        bfr[n] = *(const short8*)&Bs[row * 64 + slot * 8];
      }
      #pragma unroll
      for (int m = 0; m < 4; m++)
        #pragma unroll
        for (int n = 0; n < 4; n++)
          acc[m][n] = __builtin_amdgcn_mfma_f32_16x16x32_bf16(afr[m], bfr[n], acc[m][n], 0, 0, 0);
    }
  }

  // epilogue: C frag layout col = lane&15, row = (lane>>4)*4 + i
  #pragma unroll
  for (int n = 0; n < 4; n++){
    int col = n0 + wn * 64 + n * 16 + fr;
    float bv = bias[(size_t)e * NTOT + col];
    if (PHASE2 && sk != 0) bv = 0.f;
    #pragma unroll
    for (int m = 0; m < 4; m++){
      int rbase = m0 + wm * 64 + m * 16 + fq * 4;
      f32x4 v = acc[m][n];
      #pragma unroll
      for (int i = 0; i < 4; i++){
        int mrow = rbase + i;
        if (mrow < ne){
          int tok = lst[mrow];
          float val = v[i] + bv;
          if (PHASE2){
            pOut[((size_t)sk * T_TOK + tok) * DM + col] = val;
          } else {
            float gl = 0.5f * val * (1.0f + erff(val * 0.70710678118654752f));
            hOut[(size_t)tok * HID + col] = f2bf(gl);
          }
        }
      }
    }
  }
}

// out = gate * (part0+part1+part2+part3)   (b2 already in part0)
__global__ __launch_bounds__(256) void reduce_kernel(
    const float* __restrict__ part, const float* __restrict__ gate,
    float* __restrict__ out)
{
  size_t i = (size_t)blockIdx.x * 256 + threadIdx.x;     // float4 index
  constexpr size_t S = (size_t)T_TOK * DM / 4;
  const float4* p = (const float4*)part;
  float4 a = p[i], b = p[i + S], c = p[i + 2 * S], d = p[i + 3 * S];
  float g = gate[i >> 8];                                // 256 float4 per row
  float4 o;
  o.x = (a.x + b.x + c.x + d.x) * g;
  o.y = (a.y + b.y + c.y + d.y) * g;
  o.z = (a.z + b.z + c.z + d.z) * g;
  o.w = (a.w + b.w + c.w + d.w) * g;
  ((float4*)out)[i] = o;
}

extern "C" void kernel_launch(void* const* d_in, const int* in_sizes, int n_in,
                              void* d_out, int out_size, void* d_ws, size_t ws_size,
                              hipStream_t stream) {
  const float* x   = (const float*)d_in[0];
  const float* gw  = (const float*)d_in[1];
  const float* w1  = (const float*)d_in[2];
  const float* b1  = (const float*)d_in[3];
  const float* w2  = (const float*)d_in[4];
  const float* b2  = (const float*)d_in[5];

  char* ws = (char*)d_ws;
  float* gateo = (float*)(ws + GATE_OFF);
  int*   cnt   = (int*)  (ws + CNT_OFF);
  int*   list  = (int*)  (ws + LIST_OFF);
  float* probs = (float*)(ws + PROBS_OFF);
  u16*   xb    = (u16*)  (ws + XB_OFF);
  u16*   h     = (u16*)  (ws + H_OFF);
  u16*   w1b   = (u16*)  (ws + W1B_OFF);
  float* part  = (float*)(ws + PART_OFF);   // overlays w1b (dead after GEMM1)
  u16*   w2b   = (u16*)  (ws + W2B_OFF);

  float* out = (float*)d_out;
  float* aux = out + (size_t)T_TOK * DM;

  hipLaunchKernelGGL(zero_cnt_kernel, dim3(1), dim3(64), 0, stream, cnt);
  hipLaunchKernelGGL(gate_kernel, dim3(T_TOK / 4), dim3(256), 0, stream,
                     x, gw, gateo, cnt, list, probs, xb);
  hipLaunchKernelGGL(aux_kernel, dim3(1), dim3(256), 0, stream, probs, cnt, aux);
  hipLaunchKernelGGL(cvt2_kernel, dim3(32768), dim3(256), 0, stream, w1, w2, w1b, w2b);

  // GEMM1: xb[tok,1024] x w1b[e][4096][1024] -> h[tok][4096]
  //   ASTR=1024, BSTR=1024, NTOT=4096, NT=32, KS=16, grid = 39*32 = 1248
  hipLaunchKernelGGL((ffn_gemm<DM, DM, HID, 32, 16, false>),
                     dim3(MAXT * 32), dim3(256), 0, stream,
                     xb, w1b, b1, cnt, list, h, (float*)nullptr);
  // GEMM2: h[tok,4096] x w2b[e][1024][4096] -> PART[sk][tok][1024], split-K=4
  //   ASTR=4096, BSTR=4096, NTOT=1024, NT=8, KS=16, grid = 4*39*8 = 1248
  hipLaunchKernelGGL((ffn_gemm<HID, HID, DM, 8, 16, true>),
                     dim3(4 * MAXT * 8), dim3(256), 0, stream,
                     h, w2b, b2, cnt, list, (u16*)nullptr, part);
  hipLaunchKernelGGL(reduce_kernel, dim3(T_TOK * DM / 4 / 256), dim3(256), 0, stream,
                     part, gateo, out);
}

// Round 11
// 302.070 us; speedup vs baseline: 2.2407x; 1.0908x over previous
//
#include <hip/hip_runtime.h>
#include <math.h>

#define T_TOK 4096
#define DM 1024
#define HID 4096
#define NEXP 8
#define MAXT 39   // max total 128-row tiles: 4096/128 + 7

typedef unsigned short u16;
typedef __attribute__((ext_vector_type(8))) short short8;
typedef __attribute__((ext_vector_type(4))) float f32x4;

__device__ __forceinline__ u16 f2bf(float f){
  unsigned u = __float_as_uint(f);
  u += 0x7FFF + ((u >> 16) & 1);
  return (u16)(u >> 16);
}

// ---- workspace layout (byte offsets) ----
#define GATE_OFF   0u          // float[4096]
#define CNT_OFF    16384u      // int[8]
#define LIST_OFF   16512u      // int[8][4096]
#define PROBS_OFF  147584u     // float[4096][8]
#define XB_OFF     278656u     // bf16[4096][1024]
#define H_OFF      8667264u    // bf16[4096][4096]
#define PART_OFF   42221696u   // float[4][4096][1024] = 64MB

__device__ __forceinline__ void glds16(const void* g, void* l){
  __builtin_amdgcn_global_load_lds((const __attribute__((address_space(1))) void*)g,
                                   (__attribute__((address_space(3))) void*)l, 16, 0, 0);
}

__global__ void zero_cnt_kernel(int* cnt){
  if (threadIdx.x < NEXP) cnt[threadIdx.x] = 0;
}

// one wave per token: gating + routing + x->bf16 conversion
__global__ __launch_bounds__(256) void gate_kernel(
    const float* __restrict__ x, const float* __restrict__ gw,
    float* __restrict__ gateo, int* __restrict__ cnt, int* __restrict__ list,
    float* __restrict__ probs, u16* __restrict__ xb)
{
  int tid = threadIdx.x;
  int lane = tid & 63;
  int w = tid >> 6;
  int t = blockIdx.x * 4 + w;

  const float4* x4 = (const float4*)(x + (size_t)t * DM);
  const float4* g4 = (const float4*)gw;

  float acc[8] = {0,0,0,0,0,0,0,0};
  #pragma unroll
  for (int i = 0; i < 4; i++){
    int p = i * 64 + lane;
    float4 xv = x4[p];
    ushort4 pk;
    pk.x = f2bf(xv.x); pk.y = f2bf(xv.y); pk.z = f2bf(xv.z); pk.w = f2bf(xv.w);
    *(ushort4*)&xb[(size_t)t * DM + (size_t)p * 4] = pk;
    #pragma unroll
    for (int e = 0; e < NEXP; e++){
      float4 gv = g4[e * 256 + p];
      acc[e] += xv.x * gv.x + xv.y * gv.y + xv.z * gv.z + xv.w * gv.w;
    }
  }
  #pragma unroll
  for (int e = 0; e < NEXP; e++){
    #pragma unroll
    for (int off = 32; off; off >>= 1)
      acc[e] += __shfl_xor(acc[e], off);
  }
  if (lane == 0){
    float mx = acc[0];
    #pragma unroll
    for (int e = 1; e < NEXP; e++) mx = fmaxf(mx, acc[e]);
    float p[8]; float s = 0.f;
    #pragma unroll
    for (int e = 0; e < NEXP; e++){ p[e] = expf(acc[e] - mx); s += p[e]; }
    float inv = 1.f / s;
    int be = 0; float bp = p[0];
    #pragma unroll
    for (int e = 1; e < NEXP; e++){ if (p[e] > bp){ bp = p[e]; be = e; } }
    #pragma unroll
    for (int e = 0; e < NEXP; e++) probs[(size_t)t * 8 + e] = p[e] * inv;
    gateo[t] = bp * inv;
    int pos = atomicAdd(&cnt[be], 1);
    list[be * T_TOK + pos] = t;
  }
}

// deterministic aux-loss reduction, one block
__global__ __launch_bounds__(256) void aux_kernel(
    const float* __restrict__ probs, const int* __restrict__ cnt,
    float* __restrict__ aux_out)
{
  __shared__ float sm[256 * 8];
  int tid = threadIdx.x;
  float s[8] = {0,0,0,0,0,0,0,0};
  for (int i = 0; i < 16; i++){
    int t = i * 256 + tid;
    #pragma unroll
    for (int e = 0; e < 8; e++) s[e] += probs[(size_t)t * 8 + e];
  }
  #pragma unroll
  for (int e = 0; e < 8; e++) sm[tid * 8 + e] = s[e];
  __syncthreads();
  for (int st = 128; st; st >>= 1){
    if (tid < st){
      #pragma unroll
      for (int e = 0; e < 8; e++) sm[tid * 8 + e] += sm[(tid + st) * 8 + e];
    }
    __syncthreads();
  }
  if (tid == 0){
    float a = 0.f;
    #pragma unroll
    for (int e = 0; e < 8; e++){
      float f = (float)cnt[e] / (float)T_TOK;
      float P = sm[e] / (float)T_TOK;
      a += f * P;
    }
    aux_out[0] = 0.01f * (float)NEXP * a;
  }
}

// Grouped GEMM, m97 structure: 128x128 tile, BK=64, 4 waves (2x2), single 32KB
// LDS buffer, 2 barriers per K-step, launch_bounds(256,3) (R8 best; 4 was worse,
// 5 spilled). A: bf16 via glds16. B: fp32 DIRECT (no cvt pass) via T14 reg-stage:
// load B(ks+1) fp32 -> regs before barrier (overlaps glds-A drain), cvt f2bf
// in-reg, swizzled ds_write at top of next step. Same f2bf rounding as cvt had.
// bid = (sk*MAXT + t)*NT + nt; block scans cnt[] to decode t -> (e, mt).
// PHASE2=false: A=xb, B=w1 -> h = gelu(acc+b1) bf16
// PHASE2=true : A=h,  B=w2 -> PART[sk][tok][col] = acc (+b2 if sk==0) fp32
template<int ASTR, int BSTR, int NTOT, int NT, int KS, bool PHASE2>
__global__ __launch_bounds__(256, 3) void ffn_gemm(
    const u16*  __restrict__ Aall,
    const float* __restrict__ Bf,    // fp32 weights [E][NTOT][BSTR]
    const float* __restrict__ bias,
    const int*  __restrict__ cnt,
    const int*  __restrict__ list,
    u16*  __restrict__ hOut,
    float* __restrict__ pOut)
{
  int bid = blockIdx.x;
  int nt = bid % NT;
  int r1 = bid / NT;
  int t  = r1 % MAXT;
  int sk = r1 / MAXT;

  // decode compacted tile index -> (e, mt)   (128-row tiles)
  int e = -1, mt = 0, accT = 0;
  #pragma unroll
  for (int i = 0; i < NEXP; i++){
    int nti = (cnt[i] + 127) >> 7;
    if (e < 0 && t < accT + nti){ e = i; mt = t - accT; }
    accT += nti;
  }
  if (e < 0) return;
  int ne = cnt[e];
  int m0 = mt * 128;
  const int* lst = list + e * T_TOK;
  int n0 = nt * 128;
  int koff = sk * (KS * 64);

  __shared__ u16 As[8192];           // [128][64] swizzled, 16KB
  __shared__ u16 Bs[8192];

  int tid  = threadIdx.x;
  int lane = tid & 63;
  int w    = tid >> 6;               // 4 waves
  int wm = w >> 1, wn = w & 1;       // 2M x 2N; wave out 64x64
  int fr = lane & 15, fq = lane >> 4;

  // A staging via glds: 16 segs of 1KB (8 rows x 64 cols); wave owns 4.
  // lane l -> row seg*8+(l>>3); fetches global chunk g=(l&7)^(row&7) so
  // LDS[row][slot] holds global chunk slot^(row&7) (both-sides swizzle).
  const u16* aS[4]; int aDst[4];
  #pragma unroll
  for (int i = 0; i < 4; i++){
    int seg = w * 4 + i;
    int r   = seg * 8 + (lane >> 3);
    int g   = (lane & 7) ^ (r & 7);
    int mrow = m0 + r; if (mrow > ne - 1) mrow = ne - 1;
    aS[i] = Aall + (size_t)lst[mrow] * ASTR + koff + g * 8;
    aDst[i] = seg * 512;
  }

  // B reg-staging: 1024 chunks (128 rows x 8 slots of 8 bf16); thread owns 4.
  // chunk c = i*256+tid -> row = c>>3 (=i*32 + w*8 + (lane>>3)), slot = c&7
  // (glds-style lane map); fetches fp32 global chunk g = slot^(row&7).
  const float* bS[4]; int bDst[4];
  #pragma unroll
  for (int i = 0; i < 4; i++){
    int c = i * 256 + tid;
    int r = c >> 3, sl = c & 7;
    int g = sl ^ (r & 7);
    bS[i] = Bf + ((size_t)e * NTOT + n0 + r) * BSTR + koff + g * 8;
    bDst[i] = r * 64 + sl * 8;
  }

  f32x4 acc[4][4];
  #pragma unroll
  for (int m = 0; m < 4; m++)
    #pragma unroll
    for (int n = 0; n < 4; n++)
      acc[m][n] = (f32x4){0.f, 0.f, 0.f, 0.f};

  float4 br0[4], br1[4];
  // prologue: load B(0) into regs
  #pragma unroll
  for (int i = 0; i < 4; i++){
    const float4* s = (const float4*)bS[i];
    br0[i] = s[0]; br1[i] = s[1];
  }

  for (int ks = 0; ks < KS; ++ks){
    if (ks) __syncthreads();         // all waves done reading LDS (lgkm drained)
    size_t ko = (size_t)ks * 64;
    #pragma unroll
    for (int i = 0; i < 4; i++) glds16(aS[i] + ko, &As[aDst[i]]);
    // write B(ks) from regs (cvt fp32->bf16, swizzled chunks)
    #pragma unroll
    for (int i = 0; i < 4; i++){
      uint4 pk;
      pk.x = (unsigned)f2bf(br0[i].x) | ((unsigned)f2bf(br0[i].y) << 16);
      pk.y = (unsigned)f2bf(br0[i].z) | ((unsigned)f2bf(br0[i].w) << 16);
      pk.z = (unsigned)f2bf(br1[i].x) | ((unsigned)f2bf(br1[i].y) << 16);
      pk.w = (unsigned)f2bf(br1[i].z) | ((unsigned)f2bf(br1[i].w) << 16);
      *(uint4*)&Bs[bDst[i]] = pk;
    }
    // issue B(ks+1) reg loads; they drain at the barrier together with glds-A
    if (ks + 1 < KS){
      #pragma unroll
      for (int i = 0; i < 4; i++){
        const float4* s = (const float4*)(bS[i] + (ks + 1) * 64);
        br0[i] = s[0]; br1[i] = s[1];
      }
    }
    __syncthreads();                 // vmcnt(0)+lgkm drain: tile resident
    #pragma unroll
    for (int kc = 0; kc < 2; kc++){
      short8 afr[4], bfr[4];
      #pragma unroll
      for (int m = 0; m < 4; m++){
        int row  = wm * 64 + m * 16 + fr;
        int slot = (kc * 4 + fq) ^ (row & 7);
        afr[m] = *(const short8*)&As[row * 64 + slot * 8];
      }
      #pragma unroll
      for (int n = 0; n < 4; n++){
        int row  = wn * 64 + n * 16 + fr;
        int slot = (kc * 4 + fq) ^ (row & 7);
        bfr[n] = *(const short8*)&Bs[row * 64 + slot * 8];
      }
      #pragma unroll
      for (int m = 0; m < 4; m++)
        #pragma unroll
        for (int n = 0; n < 4; n++)
          acc[m][n] = __builtin_amdgcn_mfma_f32_16x16x32_bf16(afr[m], bfr[n], acc[m][n], 0, 0, 0);
    }
  }

  // epilogue: C frag layout col = lane&15, row = (lane>>4)*4 + i
  #pragma unroll
  for (int n = 0; n < 4; n++){
    int col = n0 + wn * 64 + n * 16 + fr;
    float bv = bias[(size_t)e * NTOT + col];
    if (PHASE2 && sk != 0) bv = 0.f;
    #pragma unroll
    for (int m = 0; m < 4; m++){
      int rbase = m0 + wm * 64 + m * 16 + fq * 4;
      f32x4 v = acc[m][n];
      #pragma unroll
      for (int i = 0; i < 4; i++){
        int mrow = rbase + i;
        if (mrow < ne){
          int tok = lst[mrow];
          float val = v[i] + bv;
          if (PHASE2){
            pOut[((size_t)sk * T_TOK + tok) * DM + col] = val;
          } else {
            float gl = 0.5f * val * (1.0f + erff(val * 0.70710678118654752f));
            hOut[(size_t)tok * HID + col] = f2bf(gl);
          }
        }
      }
    }
  }
}

// out = gate * (part0+part1+part2+part3)   (b2 already in part0)
__global__ __launch_bounds__(256) void reduce_kernel(
    const float* __restrict__ part, const float* __restrict__ gate,
    float* __restrict__ out)
{
  size_t i = (size_t)blockIdx.x * 256 + threadIdx.x;     // float4 index
  constexpr size_t S = (size_t)T_TOK * DM / 4;
  const float4* p = (const float4*)part;
  float4 a = p[i], b = p[i + S], c = p[i + 2 * S], d = p[i + 3 * S];
  float g = gate[i >> 8];                                // 256 float4 per row
  float4 o;
  o.x = (a.x + b.x + c.x + d.x) * g;
  o.y = (a.y + b.y + c.y + d.y) * g;
  o.z = (a.z + b.z + c.z + d.z) * g;
  o.w = (a.w + b.w + c.w + d.w) * g;
  ((float4*)out)[i] = o;
}

extern "C" void kernel_launch(void* const* d_in, const int* in_sizes, int n_in,
                              void* d_out, int out_size, void* d_ws, size_t ws_size,
                              hipStream_t stream) {
  const float* x   = (const float*)d_in[0];
  const float* gw  = (const float*)d_in[1];
  const float* w1  = (const float*)d_in[2];
  const float* b1  = (const float*)d_in[3];
  const float* w2  = (const float*)d_in[4];
  const float* b2  = (const float*)d_in[5];

  char* ws = (char*)d_ws;
  float* gateo = (float*)(ws + GATE_OFF);
  int*   cnt   = (int*)  (ws + CNT_OFF);
  int*   list  = (int*)  (ws + LIST_OFF);
  float* probs = (float*)(ws + PROBS_OFF);
  u16*   xb    = (u16*)  (ws + XB_OFF);
  u16*   h     = (u16*)  (ws + H_OFF);
  float* part  = (float*)(ws + PART_OFF);

  float* out = (float*)d_out;
  float* aux = out + (size_t)T_TOK * DM;

  hipLaunchKernelGGL(zero_cnt_kernel, dim3(1), dim3(64), 0, stream, cnt);
  hipLaunchKernelGGL(gate_kernel, dim3(T_TOK / 4), dim3(256), 0, stream,
                     x, gw, gateo, cnt, list, probs, xb);
  hipLaunchKernelGGL(aux_kernel, dim3(1), dim3(256), 0, stream, probs, cnt, aux);

  // GEMM1: xb[tok,1024] x w1[e][4096][1024] -> h[tok][4096]
  //   ASTR=1024, BSTR=1024, NTOT=4096, NT=32, KS=16, grid = 39*32 = 1248
  hipLaunchKernelGGL((ffn_gemm<DM, DM, HID, 32, 16, false>),
                     dim3(MAXT * 32), dim3(256), 0, stream,
                     xb, w1, b1, cnt, list, h, (float*)nullptr);
  // GEMM2: h[tok,4096] x w2[e][1024][4096] -> PART[sk][tok][1024], split-K=4
  //   ASTR=4096, BSTR=4096, NTOT=1024, NT=8, KS=16, grid = 4*39*8 = 1248
  hipLaunchKernelGGL((ffn_gemm<HID, HID, DM, 8, 16, true>),
                     dim3(4 * MAXT * 8), dim3(256), 0, stream,
                     h, w2, b2, cnt, list, (u16*)nullptr, part);
  hipLaunchKernelGGL(reduce_kernel, dim3(T_TOK * DM / 4 / 256), dim3(256), 0, stream,
                     part, gateo, out);
}